// Round 1
// baseline (248.633 us; speedup 1.0000x reference)
//
#include <hip/hip_runtime.h>

typedef __bf16 bf16x8 __attribute__((ext_vector_type(8)));
typedef float f32x4 __attribute__((ext_vector_type(4)));

#define B_  4096   // batch
#define IN_ 1024
#define H_  1024
#define KD  2048   // IN_ + H_
#define ND  4096   // 4 * H_ (gates: i,o,f,c)

__device__ __forceinline__ unsigned short f2bf(float f) {
    union { float f; unsigned u; } v; v.f = f;
    unsigned r = v.u + 0x7FFFu + ((v.u >> 16) & 1u);   // RNE
    return (unsigned short)(r >> 16);
}
__device__ __forceinline__ float bf2f(unsigned short u) {
    union { unsigned u; float f; } v; v.u = ((unsigned)u) << 16; return v.f;
}

// ---------------- pack Z = [incoming | old_h] -> bf16 [B_, KD] ----------------
__global__ __launch_bounds__(256) void pack_z(const float* __restrict__ x,
                                              const float* __restrict__ h,
                                              unsigned short* __restrict__ Z) {
    int idx = (blockIdx.x * 256 + threadIdx.x) * 4;
    int m = idx >> 11;          // / KD
    int k = idx & (KD - 1);
    const float* src = (k < IN_) ? (x + (size_t)m * IN_ + k)
                                 : (h + (size_t)m * H_ + (k - IN_));
    float4 v = *(const float4*)src;
    ushort4 o;
    o.x = f2bf(v.x); o.y = f2bf(v.y); o.z = f2bf(v.z); o.w = f2bf(v.w);
    *(ushort4*)(Z + idx) = o;
}

// ------------- pack V = [[W_i;W_o;W_f;W_c] | [U_...]] -> bf16 [ND, KD] --------
__global__ __launch_bounds__(256) void pack_v(const float* __restrict__ wi, const float* __restrict__ ui,
                                              const float* __restrict__ wo, const float* __restrict__ uo,
                                              const float* __restrict__ wf, const float* __restrict__ uf,
                                              const float* __restrict__ wc, const float* __restrict__ uc,
                                              unsigned short* __restrict__ V) {
    int idx = (blockIdx.x * 256 + threadIdx.x) * 4;
    int n = idx >> 11;          // row in [0, ND)
    int k = idx & (KD - 1);
    int g = n >> 10;            // gate 0..3 = i,o,f,c
    int r = n & (H_ - 1);
    const float* wg = (g == 0) ? wi : (g == 1) ? wo : (g == 2) ? wf : wc;
    const float* ug = (g == 0) ? ui : (g == 1) ? uo : (g == 2) ? uf : uc;
    const float* src = (k < IN_) ? (wg + (size_t)r * IN_ + k)
                                 : (ug + (size_t)r * H_ + (k - IN_));
    float4 v = *(const float4*)src;
    ushort4 o;
    o.x = f2bf(v.x); o.y = f2bf(v.y); o.z = f2bf(v.z); o.w = f2bf(v.w);
    *(ushort4*)(V + idx) = o;
}

// ---------------- GEMM: G[B_, ND] = Z[B_, KD] @ V[ND, KD]^T (bf16 out) --------
// 128x128 tile, BK=64, 4 waves (2x2) of 64x64, mfma_f32_16x16x32_bf16,
// global_load_lds width=16 staging (m97 structure).
__global__ __launch_bounds__(256) void gemm_bt(const unsigned short* __restrict__ Z,
                                               const unsigned short* __restrict__ V,
                                               unsigned short* __restrict__ G) {
    __shared__ unsigned short lA[128 * 64];
    __shared__ unsigned short lB[128 * 64];
    const int tid  = threadIdx.x;
    const int lane = tid & 63;
    const int w    = tid >> 6;
    const int wr   = w >> 1;
    const int wc   = w & 1;
    const int m0   = blockIdx.y * 128;
    const int n0   = blockIdx.x * 128;

    f32x4 acc[4][4];
#pragma unroll
    for (int i = 0; i < 4; ++i)
#pragma unroll
        for (int j = 0; j < 4; ++j) acc[i][j] = (f32x4){0.f, 0.f, 0.f, 0.f};

    // staging: 16 chunks of 1 KiB per tile; wave w owns chunks w*4 .. w*4+3.
    // chunk c covers tile rows [ (w*4+c)*8, +8 ), all 64 cols.
    // lane l -> row_in_chunk = l>>3, col = (l&7)*8 ; LDS dest = base + l*16 B.
    const int lr = lane >> 3;
    const int lc = (lane & 7) * 8;
    const unsigned short* gA = Z + (size_t)(m0 + w * 32 + lr) * KD + lc;
    const unsigned short* gB = V + (size_t)(n0 + w * 32 + lr) * KD + lc;
    unsigned short* lAw = lA + w * 32 * 64;   // = chunk (w*4) base
    unsigned short* lBw = lB + w * 32 * 64;

    const int lm = lane & 15;
    const int kq = (lane >> 4) * 8;

    for (int k0 = 0; k0 < KD; k0 += 64) {
#pragma unroll
        for (int c = 0; c < 4; ++c) {
            __builtin_amdgcn_global_load_lds(
                (const __attribute__((address_space(1))) void*)(gA + (size_t)c * 8 * KD + k0),
                (__attribute__((address_space(3))) void*)(lAw + c * 512), 16, 0, 0);
            __builtin_amdgcn_global_load_lds(
                (const __attribute__((address_space(1))) void*)(gB + (size_t)c * 8 * KD + k0),
                (__attribute__((address_space(3))) void*)(lBw + c * 512), 16, 0, 0);
        }
        __syncthreads();   // drains vmcnt(0) then barrier: LDS tiles published
#pragma unroll
        for (int ks = 0; ks < 2; ++ks) {
            bf16x8 af[4], bf[4];
            const int kb = ks * 32 + kq;
#pragma unroll
            for (int i = 0; i < 4; ++i) {
                af[i] = *(const bf16x8*)(lA + (wr * 64 + i * 16 + lm) * 64 + kb);
                bf[i] = *(const bf16x8*)(lB + (wc * 64 + i * 16 + lm) * 64 + kb);
            }
#pragma unroll
            for (int mi = 0; mi < 4; ++mi)
#pragma unroll
                for (int ni = 0; ni < 4; ++ni)
                    acc[mi][ni] = __builtin_amdgcn_mfma_f32_16x16x32_bf16(
                        af[mi], bf[ni], acc[mi][ni], 0, 0, 0);
        }
        __syncthreads();   // all reads done before next tile overwrite
    }

    // epilogue: C/D layout col = lane&15, row = (lane>>4)*4 + reg
#pragma unroll
    for (int mi = 0; mi < 4; ++mi)
#pragma unroll
        for (int ni = 0; ni < 4; ++ni)
#pragma unroll
            for (int v = 0; v < 4; ++v) {
                int row = m0 + wr * 64 + mi * 16 + (lane >> 4) * 4 + v;
                int col = n0 + wc * 64 + ni * 16 + lm;
                G[(size_t)row * ND + col] = f2bf(acc[mi][ni][v]);
            }
}

// ---------------- elementwise LSTM epilogue ----------------------------------
__global__ __launch_bounds__(256) void lstm_elt(const unsigned short* __restrict__ G,
                                                const float* __restrict__ oc,
                                                const float* __restrict__ bi,
                                                const float* __restrict__ bo,
                                                const float* __restrict__ bff,
                                                const float* __restrict__ bc,
                                                float* __restrict__ nh,
                                                float* __restrict__ nc) {
    int idx = (blockIdx.x * 256 + threadIdx.x) * 4;   // element in [0, B_*H_)
    int m = idx >> 10;
    int h = idx & (H_ - 1);
    size_t gb = (size_t)m * ND + h;
    ushort4 g0 = *(const ushort4*)(G + gb);            // gate i
    ushort4 g1 = *(const ushort4*)(G + gb + 1024);     // gate o
    ushort4 g2 = *(const ushort4*)(G + gb + 2048);     // gate f
    ushort4 g3 = *(const ushort4*)(G + gb + 3072);     // gate c
    float4 vbi = *(const float4*)(bi + h);
    float4 vbo = *(const float4*)(bo + h);
    float4 vbf = *(const float4*)(bff + h);
    float4 vbc = *(const float4*)(bc + h);
    float4 voc = *(const float4*)(oc + idx);
    float4 rh, rc;
#define COMP(c_)                                                         \
    {                                                                    \
        float gi = bf2f(g0.c_) + vbi.c_;                                 \
        float go = bf2f(g1.c_) + vbo.c_;                                 \
        float gf = bf2f(g2.c_) + vbf.c_;                                 \
        float gc = bf2f(g3.c_) + vbc.c_;                                 \
        float iv = 1.f / (1.f + __expf(-gi));                            \
        float ov = 1.f / (1.f + __expf(-go));                            \
        float fv = 1.f / (1.f + __expf(-gf));                            \
        float ct = 1.f - 2.f / (__expf(2.f * gc) + 1.f);                 \
        float cv = fv * voc.c_ + iv * ct;                                \
        float th = 1.f - 2.f / (__expf(2.f * cv) + 1.f);                 \
        rc.c_ = cv; rh.c_ = ov * th;                                     \
    }
    COMP(x) COMP(y) COMP(z) COMP(w)
#undef COMP
    *(float4*)(nh + idx) = rh;
    *(float4*)(nc + idx) = rc;
}

extern "C" void kernel_launch(void* const* d_in, const int* in_sizes, int n_in,
                              void* d_out, int out_size, void* d_ws, size_t ws_size,
                              hipStream_t stream) {
    const float* incoming = (const float*)d_in[0];
    const float* old_h    = (const float*)d_in[1];
    const float* old_c    = (const float*)d_in[2];
    const float* w_i = (const float*)d_in[3];
    const float* b_i = (const float*)d_in[4];
    const float* u_i = (const float*)d_in[5];
    const float* w_o = (const float*)d_in[6];
    const float* b_o = (const float*)d_in[7];
    const float* u_o = (const float*)d_in[8];
    const float* w_f = (const float*)d_in[9];
    const float* b_f = (const float*)d_in[10];
    const float* u_f = (const float*)d_in[11];
    const float* w_c = (const float*)d_in[12];
    const float* b_c = (const float*)d_in[13];
    const float* u_c = (const float*)d_in[14];

    unsigned short* Z = (unsigned short*)d_ws;                 // 16 MiB
    unsigned short* V = Z + (size_t)B_ * KD;                   // 16 MiB
    unsigned short* G = V + (size_t)ND * KD;                   // 32 MiB

    pack_z<<<(B_ * KD / 4) / 256, 256, 0, stream>>>(incoming, old_h, Z);
    pack_v<<<((size_t)ND * KD / 4) / 256, 256, 0, stream>>>(
        w_i, u_i, w_o, u_o, w_f, u_f, w_c, u_c, V);
    gemm_bt<<<dim3(ND / 128, B_ / 128), 256, 0, stream>>>(Z, V, G);
    lstm_elt<<<(B_ * H_ / 4) / 256, 256, 0, stream>>>(
        G, old_c, b_i, b_o, b_f, b_c,
        (float*)d_out, (float*)d_out + (size_t)B_ * H_);
}

// Round 2
// 227.429 us; speedup vs baseline: 1.0932x; 1.0932x over previous
//
#include <hip/hip_runtime.h>

typedef __bf16 bf16x8 __attribute__((ext_vector_type(8)));
typedef float f32x4 __attribute__((ext_vector_type(4)));

#define B_  4096   // batch
#define IN_ 1024
#define H_  1024
#define KD  2048   // IN_ + H_
#define ND  4096   // 4 * H_ (gates interleaved: row n = 4*h + g)

__device__ __forceinline__ unsigned short f2bf(float f) {
    union { float f; unsigned u; } v; v.f = f;
    unsigned r = v.u + 0x7FFFu + ((v.u >> 16) & 1u);   // RNE
    return (unsigned short)(r >> 16);
}

// ---------------- pack Z = [incoming | old_h] -> bf16 [B_, KD] ----------------
__global__ __launch_bounds__(256) void pack_z(const float* __restrict__ x,
                                              const float* __restrict__ h,
                                              unsigned short* __restrict__ Z) {
    int idx = (blockIdx.x * 256 + threadIdx.x) * 4;
    int m = idx >> 11;          // / KD
    int k = idx & (KD - 1);
    const float* src = (k < IN_) ? (x + (size_t)m * IN_ + k)
                                 : (h + (size_t)m * H_ + (k - IN_));
    float4 v = *(const float4*)src;
    ushort4 o;
    o.x = f2bf(v.x); o.y = f2bf(v.y); o.z = f2bf(v.z); o.w = f2bf(v.w);
    *(ushort4*)(Z + idx) = o;
}

// ------------- pack V -> bf16 [ND, KD], rows INTERLEAVED: n = 4*h + g --------
__global__ __launch_bounds__(256) void pack_v(const float* __restrict__ wi, const float* __restrict__ ui,
                                              const float* __restrict__ wo, const float* __restrict__ uo,
                                              const float* __restrict__ wf, const float* __restrict__ uf,
                                              const float* __restrict__ wc, const float* __restrict__ uc,
                                              unsigned short* __restrict__ V) {
    int idx = (blockIdx.x * 256 + threadIdx.x) * 4;
    int n = idx >> 11;          // interleaved row in [0, ND)
    int k = idx & (KD - 1);
    int g = n & 3;              // gate 0..3 = i,o,f,c
    int r = n >> 2;             // h index
    const float* wg = (g == 0) ? wi : (g == 1) ? wo : (g == 2) ? wf : wc;
    const float* ug = (g == 0) ? ui : (g == 1) ? uo : (g == 2) ? uf : uc;
    const float* src = (k < IN_) ? (wg + (size_t)r * IN_ + k)
                                 : (ug + (size_t)r * H_ + (k - IN_));
    float4 v = *(const float4*)src;
    ushort4 o;
    o.x = f2bf(v.x); o.y = f2bf(v.y); o.z = f2bf(v.z); o.w = f2bf(v.w);
    *(ushort4*)(V + idx) = o;
}

// ------- fused GEMM + LSTM: gates = Z @ V^T (+b), then elementwise cell ------
// 128x128 tile, BK=64, 4 waves (2x2) of 64x64, mfma_f32_16x16x32_bf16,
// global_load_lds width=16 staging, XOR-swizzled LDS to kill bank conflicts.
__global__ __launch_bounds__(256) void gemm_lstm(const unsigned short* __restrict__ Z,
                                                 const unsigned short* __restrict__ V,
                                                 const float* __restrict__ oc,
                                                 const float* __restrict__ bi,
                                                 const float* __restrict__ bo,
                                                 const float* __restrict__ bff,
                                                 const float* __restrict__ bc,
                                                 float* __restrict__ nh,
                                                 float* __restrict__ nc) {
    __shared__ unsigned short lA[128 * 64];
    __shared__ unsigned short lB[128 * 64];
    const int tid  = threadIdx.x;
    const int lane = tid & 63;
    const int w    = tid >> 6;
    const int wr   = w >> 1;
    const int wc   = w & 1;
    const int m0   = blockIdx.y * 128;
    const int n0   = blockIdx.x * 128;

    f32x4 acc[4][4];
#pragma unroll
    for (int i = 0; i < 4; ++i)
#pragma unroll
        for (int j = 0; j < 4; ++j) acc[i][j] = (f32x4){0.f, 0.f, 0.f, 0.f};

    // staging: 16 chunks of 1 KiB per tile; wave w owns chunks w*4 .. w*4+3.
    // chunk c covers tile rows [(w*4+c)*8, +8), all 64 cols.
    // XOR swizzle: data for col-block cb of row r lands at slot (cb ^ (r&7)).
    // global_load_lds dest is base + lane*16, so lane l (row lr=l>>3, dest
    // slot l&7) must FETCH global col-block (l&7) ^ lr.
    const int lr = lane >> 3;
    const int lc = ((lane & 7) ^ lr) * 8;
    const unsigned short* gA = Z + (size_t)(m0 + w * 32 + lr) * KD + lc;
    const unsigned short* gB = V + (size_t)(n0 + w * 32 + lr) * KD + lc;
    unsigned short* lAw = lA + w * 32 * 64;
    unsigned short* lBw = lB + w * 32 * 64;

    const int lm = lane & 15;
    const int kq = (lane >> 4) * 8;

    for (int k0 = 0; k0 < KD; k0 += 64) {
#pragma unroll
        for (int c = 0; c < 4; ++c) {
            __builtin_amdgcn_global_load_lds(
                (const __attribute__((address_space(1))) void*)(gA + (size_t)c * 8 * KD + k0),
                (__attribute__((address_space(3))) void*)(lAw + c * 512), 16, 0, 0);
            __builtin_amdgcn_global_load_lds(
                (const __attribute__((address_space(1))) void*)(gB + (size_t)c * 8 * KD + k0),
                (__attribute__((address_space(3))) void*)(lBw + c * 512), 16, 0, 0);
        }
        __syncthreads();
#pragma unroll
        for (int ks = 0; ks < 2; ++ks) {
            bf16x8 af[4], bf[4];
            const int cb = ks * 4 + (lane >> 4);   // col-block 0..7 within row
            const int sw = (cb ^ (lm & 7)) * 8;    // swizzled short-offset
#pragma unroll
            for (int i = 0; i < 4; ++i) {
                af[i] = *(const bf16x8*)(lA + (wr * 64 + i * 16 + lm) * 64 + sw);
                bf[i] = *(const bf16x8*)(lB + (wc * 64 + i * 16 + lm) * 64 + sw);
            }
#pragma unroll
            for (int mi = 0; mi < 4; ++mi)
#pragma unroll
                for (int ni = 0; ni < 4; ++ni)
                    acc[mi][ni] = __builtin_amdgcn_mfma_f32_16x16x32_bf16(
                        af[mi], bf[ni], acc[mi][ni], 0, 0, 0);
        }
        __syncthreads();
    }

    // -------- fused LSTM epilogue --------
    // acc element: row = m0+wr*64+mi*16+4a+v, col = n0+wc*64+ni*16+4b+g,
    // where a=lane>>4, b=(lane>>2)&3, g=lane&3; col = 4*h + gate.
    // XOR-shuffle gather: round t, every lane sends acc[..][(g^t)&3];
    // shfl_xor(t) delivers gate (g^t) of row (..+4a+g) to this lane.
    const int a  = lane >> 4;
    const int b  = (lane >> 2) & 3;
    const int g  = lane & 3;
    const int h0 = blockIdx.x * 32 + wc * 16;
    const int rowb = m0 + wr * 64 + 4 * a + g;

#pragma unroll
    for (int ni = 0; ni < 4; ++ni) {
        const int h = h0 + ni * 4 + b;
        const float vbi = bi[h];
        const float vbo = bo[h];
        const float vbf = bff[h];
        const float vbc = bc[h];
#pragma unroll
        for (int mi = 0; mi < 4; ++mi) {
            float recv[4];
#pragma unroll
            for (int t = 0; t < 4; ++t) {
                float x = acc[mi][ni][(g ^ t) & 3];
                recv[t] = __shfl_xor(x, t, 64);
            }
            float gi = recv[g] + vbi;
            float go = recv[g ^ 1] + vbo;
            float gf = recv[g ^ 2] + vbf;
            float gc = recv[g ^ 3] + vbc;
            const int row = rowb + mi * 16;
            const size_t off = (size_t)row * H_ + h;
            float iv = 1.f / (1.f + __expf(-gi));
            float ov = 1.f / (1.f + __expf(-go));
            float fv = 1.f / (1.f + __expf(-gf));
            float ct = 1.f - 2.f / (__expf(2.f * gc) + 1.f);
            float cv = fv * oc[off] + iv * ct;
            float th = 1.f - 2.f / (__expf(2.f * cv) + 1.f);
            nc[off] = cv;
            nh[off] = ov * th;
        }
    }
}

extern "C" void kernel_launch(void* const* d_in, const int* in_sizes, int n_in,
                              void* d_out, int out_size, void* d_ws, size_t ws_size,
                              hipStream_t stream) {
    const float* incoming = (const float*)d_in[0];
    const float* old_h    = (const float*)d_in[1];
    const float* old_c    = (const float*)d_in[2];
    const float* w_i = (const float*)d_in[3];
    const float* b_i = (const float*)d_in[4];
    const float* u_i = (const float*)d_in[5];
    const float* w_o = (const float*)d_in[6];
    const float* b_o = (const float*)d_in[7];
    const float* u_o = (const float*)d_in[8];
    const float* w_f = (const float*)d_in[9];
    const float* b_f = (const float*)d_in[10];
    const float* u_f = (const float*)d_in[11];
    const float* w_c = (const float*)d_in[12];
    const float* b_c = (const float*)d_in[13];
    const float* u_c = (const float*)d_in[14];

    unsigned short* Z = (unsigned short*)d_ws;                 // 16 MiB
    unsigned short* V = Z + (size_t)B_ * KD;                   // 16 MiB

    pack_z<<<(B_ * KD / 4) / 256, 256, 0, stream>>>(incoming, old_h, Z);
    pack_v<<<((size_t)ND * KD / 4) / 256, 256, 0, stream>>>(
        w_i, u_i, w_o, u_o, w_f, u_f, w_c, u_c, V);
    gemm_lstm<<<dim3(ND / 128, B_ / 128), 256, 0, stream>>>(
        Z, V, old_c, b_i, b_o, b_f, b_c,
        (float*)d_out, (float*)d_out + (size_t)B_ * H_);
}